// Round 9
// baseline (355.294 us; speedup 1.0000x reference)
//
#include <hip/hip_runtime.h>

#define D 256
#define KDIM 512
#define BCAP 16384  // per-bucket staging capacity (avg fill 8192 for E=3.2M, B1=391)
#define EPB 8192    // edges per scatter block
#define BM 64       // rows per GEMM block

typedef __bf16 bf16_t;
typedef bf16_t bf16x8 __attribute__((ext_vector_type(8)));
typedef bf16_t bf16x4 __attribute__((ext_vector_type(4)));
typedef float f32x4_t __attribute__((ext_vector_type(4)));
typedef float f32x2_t __attribute__((ext_vector_type(2)));

// async global->LDS, 16B/lane; LDS dest is wave-uniform base + lane*16
__device__ __forceinline__ void async_cp16(const void* g, void* l) {
    __builtin_amdgcn_global_load_lds(
        (const __attribute__((address_space(1))) unsigned int*)g,
        (__attribute__((address_space(3))) unsigned int*)l, 16, 0, 0);
}

// ---------------- CSR build (bucketed, block-aggregated scatter) -----------

__global__ __launch_bounds__(256) void k_scatter1(const int* __restrict__ eidx,
                                                  int* __restrict__ bcur,
                                                  int* __restrict__ staging, int E) {
    __shared__ int lhist[512];
    __shared__ int lcur[512];
    __shared__ int gbase[512];
    const int t = threadIdx.x;
    const int e0 = blockIdx.x * EPB;
    int e1 = e0 + EPB;
    if (e1 > E) e1 = E;

    lhist[t] = 0;
    lhist[t + 256] = 0;
    lcur[t] = 0;
    lcur[t + 256] = 0;
    __syncthreads();

    for (int e = e0 + t; e < e1; e += 256) {
        int d = eidx[E + e];
        atomicAdd(&lhist[d >> 8], 1);
    }
    __syncthreads();

#pragma unroll
    for (int b = t; b < 512; b += 256) {
        int c = lhist[b];
        gbase[b] = (c > 0) ? atomicAdd(&bcur[b * 16], c) : 0;
    }
    __syncthreads();

    for (int e = e0 + t; e < e1; e += 256) {
        int s = eidx[e];
        int d = eidx[E + e];
        int b = d >> 8;
        int pos = gbase[b] + atomicAdd(&lcur[b], 1);
        staging[(size_t)b * BCAP + pos] = ((d & 255) << 24) | s;  // s < 2^24
    }
}

__global__ __launch_bounds__(512) void k_bbase(const int* __restrict__ bcur,
                                               int* __restrict__ bbase,
                                               int* __restrict__ row_ptr,
                                               int B1, int N, int E) {
    __shared__ int sm[512];
    int t = threadIdx.x;
    int v = (t < B1) ? bcur[t * 16] : 0;
    sm[t] = v;
    __syncthreads();
    for (int off = 1; off < 512; off <<= 1) {
        int u = (t >= off) ? sm[t - off] : 0;
        __syncthreads();
        sm[t] += u;
        __syncthreads();
    }
    if (t < B1) bbase[t] = sm[t] - v;  // exclusive
    if (t == 0) row_ptr[N] = E;
}

__global__ __launch_bounds__(256) void k_bucket(const int* __restrict__ bcur,
                                                const int* __restrict__ bbase,
                                                const int* __restrict__ staging,
                                                int* __restrict__ edge_src,
                                                int* __restrict__ row_ptr, int N) {
    __shared__ int lhist[256];
    __shared__ int lscan[256];
    __shared__ int lcur[256];
    int b = blockIdx.x, t = threadIdx.x;
    int node_base = b << 8;
    int nn = N - node_base;
    if (nn > 256) nn = 256;
    int cnt = bcur[b * 16];
    int base = bbase[b];
    const int* stg = staging + (size_t)b * BCAP;

    lhist[t] = 0;
    __syncthreads();
    for (int i = t; i < cnt; i += 256)
        atomicAdd(&lhist[((unsigned)stg[i]) >> 24], 1);
    __syncthreads();
    int v = lhist[t];
    lscan[t] = v;
    __syncthreads();
    for (int off = 1; off < 256; off <<= 1) {
        int u = (t >= off) ? lscan[t - off] : 0;
        __syncthreads();
        lscan[t] += u;
        __syncthreads();
    }
    int excl = lscan[t] - v;
    if (t < nn) row_ptr[node_base + t] = base + excl;
    lscan[t] = excl;
    lcur[t] = 0;
    __syncthreads();
    for (int i = t; i < cnt; i += 256) {
        int w = stg[i];
        int ln = ((unsigned)w) >> 24;
        int src = w & 0xFFFFFF;
        int pos = base + lscan[ln] + atomicAdd(&lcur[ln], 1);
        edge_src[pos] = src;
    }
}

// ---------------- conversions ----------------

// x (f32) -> Xq (fp8 e4m3, gather table) AND Xb (bf16, linear)
__global__ __launch_bounds__(256) void k_convx(const float* __restrict__ x,
                                               unsigned int* __restrict__ Xq,
                                               bf16_t* __restrict__ Xb,
                                               int total8) {
    int i = blockIdx.x * 256 + threadIdx.x;  // one thread = 8 elems
    if (i >= total8) return;
    float4 v0 = *(const float4*)(x + (size_t)i * 8);
    float4 v1 = *(const float4*)(x + (size_t)i * 8 + 4);
    int w0 = 0, w1 = 0;
    w0 = __builtin_amdgcn_cvt_pk_fp8_f32(v0.x, v0.y, w0, false);
    w0 = __builtin_amdgcn_cvt_pk_fp8_f32(v0.z, v0.w, w0, true);
    w1 = __builtin_amdgcn_cvt_pk_fp8_f32(v1.x, v1.y, w1, false);
    w1 = __builtin_amdgcn_cvt_pk_fp8_f32(v1.z, v1.w, w1, true);
    uint2 o = {(unsigned)w0, (unsigned)w1};
    *(uint2*)(Xq + (size_t)i * 2) = o;
    bf16x8 ob = {(bf16_t)v0.x, (bf16_t)v0.y, (bf16_t)v0.z, (bf16_t)v0.w,
                 (bf16_t)v1.x, (bf16_t)v1.y, (bf16_t)v1.z, (bf16_t)v1.w};
    *(bf16x8*)(Xb + (size_t)i * 8) = ob;
}

// Wcat [256][512] bf16: [:,0:256]=W_l, [:,256:512]=W_r
__global__ __launch_bounds__(256) void k_convw(const float* __restrict__ Wl,
                                               const float* __restrict__ Wr,
                                               bf16_t* __restrict__ Wcat) {
    int i = blockIdx.x * 256 + threadIdx.x;
    if (i >= D * KDIM / 4) return;
    int o = i * 4;
    int j = o >> 9;
    int k = o & 511;
    const float* src = (k < D) ? (Wl + (size_t)j * D + k)
                               : (Wr + (size_t)j * D + (k - D));
    float4 v = *(const float4*)src;
    bf16x4 ov = {(bf16_t)v.x, (bf16_t)v.y, (bf16_t)v.z, (bf16_t)v.w};
    *(bf16x4*)(Wcat + o) = ov;
}

// ------- aggregation: one wave per node, 4 fp8 rows per load instruction ----

__global__ __launch_bounds__(256) void k_aggregate(const int* __restrict__ row_ptr,
                                                   const int* __restrict__ edge_src,
                                                   const unsigned int* __restrict__ Xq,
                                                   bf16_t* __restrict__ Agg, int N) {
    int wv = threadIdx.x >> 6;
    int lane = threadIdx.x & 63;
    int node = blockIdx.x * 4 + wv;
    if (node >= N) return;
    int g = lane >> 4;       // row group 0..3
    int c = lane & 15;       // 16-fp8 column chunk
    int beg = row_ptr[node];
    int end = row_ptr[node + 1];

    float acc[16];
#pragma unroll
    for (int k = 0; k < 16; k++) acc[k] = 0.f;

#define ACC4(w, bidx)                                            \
    {                                                            \
        f32x2_t lo = __builtin_amdgcn_cvt_pk_f32_fp8((w), false);\
        f32x2_t hi = __builtin_amdgcn_cvt_pk_f32_fp8((w), true); \
        acc[(bidx) + 0] += lo[0];                                \
        acc[(bidx) + 1] += lo[1];                                \
        acc[(bidx) + 2] += hi[0];                                \
        acc[(bidx) + 3] += hi[1];                                \
    }

    for (int j = beg; j < end; j += 8) {
        int j0 = j + g, j1 = j + 4 + g;
        bool ok0 = j0 < end, ok1 = j1 < end;
        int s0 = edge_src[ok0 ? j0 : beg];
        int s1 = edge_src[ok1 ? j1 : beg];
        uint4 v0 = *(const uint4*)(Xq + (size_t)s0 * 64 + c * 4);
        uint4 v1 = *(const uint4*)(Xq + (size_t)s1 * 64 + c * 4);
        if (!ok0) { v0.x = 0; v0.y = 0; v0.z = 0; v0.w = 0; }
        if (!ok1) { v1.x = 0; v1.y = 0; v1.z = 0; v1.w = 0; }
        ACC4(v0.x, 0) ACC4(v0.y, 4) ACC4(v0.z, 8) ACC4(v0.w, 12)
        ACC4(v1.x, 0) ACC4(v1.y, 4) ACC4(v1.z, 8) ACC4(v1.w, 12)
    }
#undef ACC4

#pragma unroll
    for (int k = 0; k < 16; k++) {
        acc[k] += __shfl_xor(acc[k], 16, 64);
        acc[k] += __shfl_xor(acc[k], 32, 64);
    }
    int dg = end - beg;
    float inv = 1.0f / (float)(dg > 0 ? dg : 1);
    if (g == 0) {  // lanes 0..15 write 32B each = full 512B row
        bf16x8 o0 = {(bf16_t)(acc[0] * inv), (bf16_t)(acc[1] * inv),
                     (bf16_t)(acc[2] * inv), (bf16_t)(acc[3] * inv),
                     (bf16_t)(acc[4] * inv), (bf16_t)(acc[5] * inv),
                     (bf16_t)(acc[6] * inv), (bf16_t)(acc[7] * inv)};
        bf16x8 o1 = {(bf16_t)(acc[8] * inv), (bf16_t)(acc[9] * inv),
                     (bf16_t)(acc[10] * inv), (bf16_t)(acc[11] * inv),
                     (bf16_t)(acc[12] * inv), (bf16_t)(acc[13] * inv),
                     (bf16_t)(acc[14] * inv), (bf16_t)(acc[15] * inv)};
        *(bf16x8*)(Agg + (size_t)node * D + c * 16) = o0;
        *(bf16x8*)(Agg + (size_t)node * D + c * 16 + 8) = o1;
    }
}

// ------- GEMM: full-K A-panel in LDS (staged once), barrier-free k-loop,
//         B (Wcat, L2-hot) direct-to-register; fused GELU+LN+residual. -----
// 256 thr = 4 waves; block = 64 rows x 256 cols; wave = 64 rows x 64 cols.
// A_lds[64][512] bf16; 16B-block index swizzled blk' = blk ^ (row&7)
// (rule #21: linear DMA dest + per-lane inverse-swizzled global source).

__global__ __launch_bounds__(256) void k_gemm(
        const bf16_t* __restrict__ Agg, const bf16_t* __restrict__ Xb,
        const bf16_t* __restrict__ Wcat, const float* __restrict__ b_l,
        const float* __restrict__ gamma, const float* __restrict__ beta,
        float* __restrict__ out, int M) {
    __shared__ __align__(16) bf16_t A_lds[BM * KDIM];  // 64 KB
    __shared__ float sm_s[4][BM];
    __shared__ float sm_q[4][BM];

    const int tid = threadIdx.x;
    const int lane = tid & 63;
    const int wid = tid >> 6;   // wave -> 64-col strip
    const int lr = lane & 15;
    const int lh = lane >> 4;
    const int row0 = blockIdx.x * BM;

    // ---- stage A panel: logical row r = [Agg_r (blk 0..31) | Xb_r (blk 32..63)]
    // one 1KB LDS row per (call o, wave); lane l's dst slot l holds logical
    // block l^(r&7)  (XOR stays within each 32-block half).
#pragma unroll
    for (int o = 0; o < 16; ++o) {
        int r = o * 4 + wid;
        int gr = row0 + r;
        if (gr > M - 1) gr = M - 1;
        int lb = lane ^ (r & 7);
        const bf16_t* src = (lane < 32) ? (Agg + (size_t)gr * D + lb * 8)
                                        : (Xb + (size_t)gr * D + (lb - 32) * 8);
        async_cp16(src, &A_lds[r * KDIM]);
    }
    __syncthreads();  // compiler drains vmcnt before barrier

    // ---- barrier-free K loop ----
    f32x4_t acc[4][4];
#pragma unroll
    for (int i = 0; i < 4; i++)
#pragma unroll
        for (int j = 0; j < 4; j++) acc[i][j] = (f32x4_t){0.f, 0.f, 0.f, 0.f};

    const bf16_t* wb = Wcat + (size_t)(wid * 64 + lr) * KDIM;

#pragma unroll 4
    for (int k0 = 0; k0 < KDIM; k0 += 32) {
        const int kb = (k0 >> 3) + lh;  // logical 16B-block 0..63
        bf16x8 a[4], b[4];
#pragma unroll
        for (int mt = 0; mt < 4; mt++) {
            int ra = mt * 16 + lr;
            a[mt] = *(const bf16x8*)&A_lds[ra * KDIM + ((kb ^ (ra & 7)) << 3)];
        }
#pragma unroll
        for (int nt = 0; nt < 4; nt++)
            b[nt] = *(const bf16x8*)(wb + (size_t)nt * 16 * KDIM + k0 + lh * 8);
#pragma unroll
        for (int mt = 0; mt < 4; mt++)
#pragma unroll
            for (int nt = 0; nt < 4; nt++)
                acc[mt][nt] = __builtin_amdgcn_mfma_f32_16x16x32_bf16(
                    a[mt], b[nt], acc[mt][nt], 0, 0, 0);
    }

    // ---- fused epilogue: bias + exact GELU + LayerNorm + residual(LDS) ----
    // C/D layout: col = lane&15, row = (lane>>4)*4 + reg
    float bl[4], ga[4], be[4];
#pragma unroll
    for (int nt = 0; nt < 4; nt++) {
        int c = wid * 64 + nt * 16 + lr;
        bl[nt] = b_l[c];
        ga[nt] = gamma[c];
        be[nt] = beta[c];
    }

#pragma unroll
    for (int mt = 0; mt < 4; mt++) {
#pragma unroll
        for (int r = 0; r < 4; r++) {
            float s = 0.f, q = 0.f;
#pragma unroll
            for (int nt = 0; nt < 4; nt++) {
                float u = acc[mt][nt][r] + bl[nt];
                float ge = 0.5f * u * (1.0f + erff(u * 0.70710678118654752f));
                acc[mt][nt][r] = ge;
                s += ge;
                q += ge * ge;
            }
#pragma unroll
            for (int off = 8; off >= 1; off >>= 1) {
                s += __shfl_xor(s, off, 64);
                q += __shfl_xor(q, off, 64);
            }
            if (lr == 0) {
                int rl = mt * 16 + lh * 4 + r;
                sm_s[wid][rl] = s;
                sm_q[wid][rl] = q;
            }
        }
    }
    __syncthreads();

#pragma unroll
    for (int mt = 0; mt < 4; mt++) {
#pragma unroll
        for (int r = 0; r < 4; r++) {
            int rl = mt * 16 + lh * 4 + r;
            int m = row0 + rl;
            float S = sm_s[0][rl] + sm_s[1][rl] + sm_s[2][rl] + sm_s[3][rl];
            float Q = sm_q[0][rl] + sm_q[1][rl] + sm_q[2][rl] + sm_q[3][rl];
            float mean = S * (1.0f / 256.0f);
            float var = Q * (1.0f / 256.0f) - mean * mean;
            float rstd = rsqrtf(var + 1e-5f);
            if (m < M) {
#pragma unroll
                for (int nt = 0; nt < 4; nt++) {
                    int c = wid * 64 + nt * 16 + lr;
                    int pb = (32 + (c >> 3)) ^ (rl & 7);  // Xb half, swizzled
                    float res = (float)A_lds[rl * KDIM + pb * 8 + (c & 7)];
                    out[(size_t)m * D + c] =
                        (acc[mt][nt][r] - mean) * rstd * ga[nt] + be[nt] + res;
                }
            }
        }
    }
}

// ---------------- launch ----------------

extern "C" void kernel_launch(void* const* d_in, const int* in_sizes, int n_in,
                              void* d_out, int out_size, void* d_ws, size_t ws_size,
                              hipStream_t stream) {
    const float* x = (const float*)d_in[0];
    const int* eidx = (const int*)d_in[1];
    const float* W_l = (const float*)d_in[2];
    const float* b_l = (const float*)d_in[3];
    const float* W_r = (const float*)d_in[4];
    const float* gamma = (const float*)d_in[5];
    const float* beta = (const float*)d_in[6];
    float* out = (float*)d_out;

    const int N = in_sizes[0] / D;
    const int E = in_sizes[1] / 2;
    const int B1 = (N + 255) >> 8;  // 256-node buckets

    char* basep = (char*)d_ws;
    size_t off = 0;
    auto take = [&](size_t bytes) -> void* {
        void* r = basep + off;
        off += (bytes + 255) & ~(size_t)255;
        return r;
    };
    bf16_t* Agg = (bf16_t*)take((size_t)N * D * sizeof(bf16_t));       // 51.2 MB
    bf16_t* Xb = (bf16_t*)take((size_t)N * D * sizeof(bf16_t));        // 51.2 MB
    unsigned int* Xq = (unsigned int*)take((size_t)N * (D / 4) * 4);   // 25.6 MB
    int* edge_src = (int*)take((size_t)E * sizeof(int));               // 12.8 MB
    bf16_t* Wcat = (bf16_t*)take((size_t)D * KDIM * sizeof(bf16_t));
    int* row_ptr = (int*)take((size_t)(N + 1) * sizeof(int));
    int* bcur = (int*)take((size_t)B1 * 16 * sizeof(int));
    int* bbase = (int*)take((size_t)B1 * sizeof(int));
    // staging (B1*BCAP ints = 25.6MB) aliases Agg (51.2MB): consumed by
    // k_bucket strictly BEFORE k_aggregate writes Agg.
    int* staging = (int*)Agg;

    hipMemsetAsync(bcur, 0, (size_t)B1 * 16 * sizeof(int), stream);

    k_scatter1<<<(E + EPB - 1) / EPB, 256, 0, stream>>>(eidx, bcur, staging, E);
    k_bbase<<<1, 512, 0, stream>>>(bcur, bbase, row_ptr, B1, N, E);
    k_bucket<<<B1, 256, 0, stream>>>(bcur, bbase, staging, edge_src, row_ptr, N);

    k_convx<<<(N * (D / 8) + 255) / 256, 256, 0, stream>>>(x, Xq, Xb, N * (D / 8));
    k_convw<<<(D * KDIM / 4 + 255) / 256, 256, 0, stream>>>(W_l, W_r, Wcat);

    k_aggregate<<<(N + 3) / 4, 256, 0, stream>>>(row_ptr, edge_src, Xq, Agg, N);

    k_gemm<<<(N + BM - 1) / BM, 256, 0, stream>>>(Agg, Xb, Wcat, b_l, gamma,
                                                  beta, out, N);
}

// Round 10
// 350.435 us; speedup vs baseline: 1.0139x; 1.0139x over previous
//
#include <hip/hip_runtime.h>

#define D 256
#define KDIM 512
#define BCAP 16384  // per-bucket staging capacity (avg fill 8192 for E=3.2M, B1=391)
#define EPB 8192    // edges per scatter block
#define BM 64       // rows per GEMM block

typedef __bf16 bf16_t;
typedef bf16_t bf16x8 __attribute__((ext_vector_type(8)));
typedef bf16_t bf16x4 __attribute__((ext_vector_type(4)));
typedef float f32x4_t __attribute__((ext_vector_type(4)));
typedef float f32x2_t __attribute__((ext_vector_type(2)));

// async global->LDS, 16B/lane; LDS dest is wave-uniform base + lane*16
__device__ __forceinline__ void async_cp16(const void* g, void* l) {
    __builtin_amdgcn_global_load_lds(
        (const __attribute__((address_space(1))) unsigned int*)g,
        (__attribute__((address_space(3))) unsigned int*)l, 16, 0, 0);
}

// ---------------- CSR build (bucketed, block-aggregated scatter) -----------

__global__ __launch_bounds__(256) void k_scatter1(const int* __restrict__ eidx,
                                                  int* __restrict__ bcur,
                                                  int* __restrict__ staging, int E) {
    __shared__ int lhist[512];
    __shared__ int lcur[512];
    __shared__ int gbase[512];
    const int t = threadIdx.x;
    const int e0 = blockIdx.x * EPB;
    int e1 = e0 + EPB;
    if (e1 > E) e1 = E;

    lhist[t] = 0;
    lhist[t + 256] = 0;
    lcur[t] = 0;
    lcur[t + 256] = 0;
    __syncthreads();

    for (int e = e0 + t; e < e1; e += 256) {
        int d = eidx[E + e];
        atomicAdd(&lhist[d >> 8], 1);
    }
    __syncthreads();

#pragma unroll
    for (int b = t; b < 512; b += 256) {
        int c = lhist[b];
        gbase[b] = (c > 0) ? atomicAdd(&bcur[b * 16], c) : 0;
    }
    __syncthreads();

    for (int e = e0 + t; e < e1; e += 256) {
        int s = eidx[e];
        int d = eidx[E + e];
        int b = d >> 8;
        int pos = gbase[b] + atomicAdd(&lcur[b], 1);
        staging[(size_t)b * BCAP + pos] = ((d & 255) << 24) | s;  // s < 2^24
    }
}

__global__ __launch_bounds__(512) void k_bbase(const int* __restrict__ bcur,
                                               int* __restrict__ bbase,
                                               int* __restrict__ row_ptr,
                                               int B1, int N, int E) {
    __shared__ int sm[512];
    int t = threadIdx.x;
    int v = (t < B1) ? bcur[t * 16] : 0;
    sm[t] = v;
    __syncthreads();
    for (int off = 1; off < 512; off <<= 1) {
        int u = (t >= off) ? sm[t - off] : 0;
        __syncthreads();
        sm[t] += u;
        __syncthreads();
    }
    if (t < B1) bbase[t] = sm[t] - v;  // exclusive
    if (t == 0) row_ptr[N] = E;
}

__global__ __launch_bounds__(256) void k_bucket(const int* __restrict__ bcur,
                                                const int* __restrict__ bbase,
                                                const int* __restrict__ staging,
                                                int* __restrict__ edge_src,
                                                int* __restrict__ row_ptr, int N) {
    __shared__ int lhist[256];
    __shared__ int lscan[256];
    __shared__ int lcur[256];
    int b = blockIdx.x, t = threadIdx.x;
    int node_base = b << 8;
    int nn = N - node_base;
    if (nn > 256) nn = 256;
    int cnt = bcur[b * 16];
    int base = bbase[b];
    const int* stg = staging + (size_t)b * BCAP;

    lhist[t] = 0;
    __syncthreads();
    for (int i = t; i < cnt; i += 256)
        atomicAdd(&lhist[((unsigned)stg[i]) >> 24], 1);
    __syncthreads();
    int v = lhist[t];
    lscan[t] = v;
    __syncthreads();
    for (int off = 1; off < 256; off <<= 1) {
        int u = (t >= off) ? lscan[t - off] : 0;
        __syncthreads();
        lscan[t] += u;
        __syncthreads();
    }
    int excl = lscan[t] - v;
    if (t < nn) row_ptr[node_base + t] = base + excl;
    lscan[t] = excl;
    lcur[t] = 0;
    __syncthreads();
    for (int i = t; i < cnt; i += 256) {
        int w = stg[i];
        int ln = ((unsigned)w) >> 24;
        int src = w & 0xFFFFFF;
        int pos = base + lscan[ln] + atomicAdd(&lcur[ln], 1);
        edge_src[pos] = src;
    }
}

// ---------------- conversions ----------------

// x (f32) -> Xq (fp8 e4m3, gather table) AND Xb (bf16, linear)
__global__ __launch_bounds__(256) void k_convx(const float* __restrict__ x,
                                               unsigned int* __restrict__ Xq,
                                               bf16_t* __restrict__ Xb,
                                               int total8) {
    int i = blockIdx.x * 256 + threadIdx.x;  // one thread = 8 elems
    if (i >= total8) return;
    float4 v0 = *(const float4*)(x + (size_t)i * 8);
    float4 v1 = *(const float4*)(x + (size_t)i * 8 + 4);
    int w0 = 0, w1 = 0;
    w0 = __builtin_amdgcn_cvt_pk_fp8_f32(v0.x, v0.y, w0, false);
    w0 = __builtin_amdgcn_cvt_pk_fp8_f32(v0.z, v0.w, w0, true);
    w1 = __builtin_amdgcn_cvt_pk_fp8_f32(v1.x, v1.y, w1, false);
    w1 = __builtin_amdgcn_cvt_pk_fp8_f32(v1.z, v1.w, w1, true);
    uint2 o = {(unsigned)w0, (unsigned)w1};
    *(uint2*)(Xq + (size_t)i * 2) = o;
    bf16x8 ob = {(bf16_t)v0.x, (bf16_t)v0.y, (bf16_t)v0.z, (bf16_t)v0.w,
                 (bf16_t)v1.x, (bf16_t)v1.y, (bf16_t)v1.z, (bf16_t)v1.w};
    *(bf16x8*)(Xb + (size_t)i * 8) = ob;
}

// Wcat [256][512] bf16: [:,0:256]=W_l, [:,256:512]=W_r
__global__ __launch_bounds__(256) void k_convw(const float* __restrict__ Wl,
                                               const float* __restrict__ Wr,
                                               bf16_t* __restrict__ Wcat) {
    int i = blockIdx.x * 256 + threadIdx.x;
    if (i >= D * KDIM / 4) return;
    int o = i * 4;
    int j = o >> 9;
    int k = o & 511;
    const float* src = (k < D) ? (Wl + (size_t)j * D + k)
                               : (Wr + (size_t)j * D + (k - D));
    float4 v = *(const float4*)src;
    bf16x4 ov = {(bf16_t)v.x, (bf16_t)v.y, (bf16_t)v.z, (bf16_t)v.w};
    *(bf16x4*)(Wcat + o) = ov;
}

// ------- aggregation: one wave per node, 4 fp8 rows per load instruction ----

__global__ __launch_bounds__(256) void k_aggregate(const int* __restrict__ row_ptr,
                                                   const int* __restrict__ edge_src,
                                                   const unsigned int* __restrict__ Xq,
                                                   bf16_t* __restrict__ Agg, int N) {
    int wv = threadIdx.x >> 6;
    int lane = threadIdx.x & 63;
    int node = blockIdx.x * 4 + wv;
    if (node >= N) return;
    int g = lane >> 4;       // row group 0..3
    int c = lane & 15;       // 16-fp8 column chunk
    int beg = row_ptr[node];
    int end = row_ptr[node + 1];

    float acc[16];
#pragma unroll
    for (int k = 0; k < 16; k++) acc[k] = 0.f;

#define ACC4(w, bidx)                                            \
    {                                                            \
        f32x2_t lo = __builtin_amdgcn_cvt_pk_f32_fp8((w), false);\
        f32x2_t hi = __builtin_amdgcn_cvt_pk_f32_fp8((w), true); \
        acc[(bidx) + 0] += lo[0];                                \
        acc[(bidx) + 1] += lo[1];                                \
        acc[(bidx) + 2] += hi[0];                                \
        acc[(bidx) + 3] += hi[1];                                \
    }

    for (int j = beg; j < end; j += 8) {
        int j0 = j + g, j1 = j + 4 + g;
        bool ok0 = j0 < end, ok1 = j1 < end;
        int s0 = edge_src[ok0 ? j0 : beg];
        int s1 = edge_src[ok1 ? j1 : beg];
        uint4 v0 = *(const uint4*)(Xq + (size_t)s0 * 64 + c * 4);
        uint4 v1 = *(const uint4*)(Xq + (size_t)s1 * 64 + c * 4);
        if (!ok0) { v0.x = 0; v0.y = 0; v0.z = 0; v0.w = 0; }
        if (!ok1) { v1.x = 0; v1.y = 0; v1.z = 0; v1.w = 0; }
        ACC4(v0.x, 0) ACC4(v0.y, 4) ACC4(v0.z, 8) ACC4(v0.w, 12)
        ACC4(v1.x, 0) ACC4(v1.y, 4) ACC4(v1.z, 8) ACC4(v1.w, 12)
    }
#undef ACC4

#pragma unroll
    for (int k = 0; k < 16; k++) {
        acc[k] += __shfl_xor(acc[k], 16, 64);
        acc[k] += __shfl_xor(acc[k], 32, 64);
    }
    int dg = end - beg;
    float inv = 1.0f / (float)(dg > 0 ? dg : 1);
    if (g == 0) {  // lanes 0..15 write 32B each = full 512B row
        bf16x8 o0 = {(bf16_t)(acc[0] * inv), (bf16_t)(acc[1] * inv),
                     (bf16_t)(acc[2] * inv), (bf16_t)(acc[3] * inv),
                     (bf16_t)(acc[4] * inv), (bf16_t)(acc[5] * inv),
                     (bf16_t)(acc[6] * inv), (bf16_t)(acc[7] * inv)};
        bf16x8 o1 = {(bf16_t)(acc[8] * inv), (bf16_t)(acc[9] * inv),
                     (bf16_t)(acc[10] * inv), (bf16_t)(acc[11] * inv),
                     (bf16_t)(acc[12] * inv), (bf16_t)(acc[13] * inv),
                     (bf16_t)(acc[14] * inv), (bf16_t)(acc[15] * inv)};
        *(bf16x8*)(Agg + (size_t)node * D + c * 16) = o0;
        *(bf16x8*)(Agg + (size_t)node * D + c * 16 + 8) = o1;
    }
}

// ------- GEMM: K split in 2 halves; A-half panel (32KB) in LDS; barrier-free
//         k-loops; B (Wcat, L2-hot) direct-to-register; fused GELU+LN+res. --
// 256 thr = 4 waves; block = 64 rows x 256 cols; 4 blocks/CU (36KB LDS).
// A_lds[64][256] bf16; 16B-block (32/row) swizzle blk' = blk ^ ((row&7)<<2).

__global__ __launch_bounds__(256) void k_gemm(
        const bf16_t* __restrict__ Agg, const bf16_t* __restrict__ Xb,
        const bf16_t* __restrict__ Wcat, const float* __restrict__ b_l,
        const float* __restrict__ gamma, const float* __restrict__ beta,
        float* __restrict__ out, int M) {
    __shared__ __align__(16) bf16_t A_lds[BM * D];  // 32 KB
    __shared__ float sm_s[4][BM];
    __shared__ float sm_q[4][BM];

    const int tid = threadIdx.x;
    const int lane = tid & 63;
    const int wid = tid >> 6;   // wave -> 64-col strip
    const int lr = lane & 15;
    const int lh = lane >> 4;
    const int row0 = blockIdx.x * BM;

    // staging: 8 cp16/thread; idx = o*256+tid; row r = idx>>5, 16B-block j = idx&31
    // LDS dst = idx*16 bytes (wave-uniform base + lane*16); global src block
    // pre-inverse-swizzled: lb = j ^ ((r&7)<<2).
    const int s_r = tid >> 5;        // base row for o=0 (0..7)
    const int s_j = tid & 31;
#define STAGE_PANEL(srcbase)                                                   \
    do {                                                                       \
        _Pragma("unroll") for (int o = 0; o < 8; ++o) {                        \
            int r = o * 8 + s_r;                                               \
            int gr = row0 + r;                                                 \
            if (gr > M - 1) gr = M - 1;                                        \
            int lb = s_j ^ ((r & 7) << 2);                                     \
            async_cp16((srcbase) + (size_t)gr * D + lb * 8,                    \
                       &A_lds[(o * 256 + tid) * 8]);                           \
        }                                                                      \
    } while (0)

    f32x4_t acc[4][4];
#pragma unroll
    for (int i = 0; i < 4; i++)
#pragma unroll
        for (int j = 0; j < 4; j++) acc[i][j] = (f32x4_t){0.f, 0.f, 0.f, 0.f};

    const bf16_t* wb = Wcat + (size_t)(wid * 64 + lr) * KDIM;

#define KHALF(koff)                                                            \
    _Pragma("unroll") for (int k0 = 0; k0 < 256; k0 += 32) {                   \
        const int kb = (k0 >> 3) + lh; /* logical 16B-block 0..31 */           \
        bf16x8 a[4], b[4];                                                     \
        _Pragma("unroll") for (int mt = 0; mt < 4; mt++) {                     \
            int ra = mt * 16 + lr;                                             \
            a[mt] = *(const bf16x8*)&A_lds[ra * D +                            \
                                           ((kb ^ ((lr & 7) << 2)) << 3)];     \
        }                                                                      \
        _Pragma("unroll") for (int nt = 0; nt < 4; nt++)                       \
            b[nt] = *(const bf16x8*)(wb + (size_t)nt * 16 * KDIM + (koff) +    \
                                     k0 + lh * 8);                             \
        _Pragma("unroll") for (int mt = 0; mt < 4; mt++)                       \
            _Pragma("unroll") for (int nt = 0; nt < 4; nt++)                   \
                acc[mt][nt] = __builtin_amdgcn_mfma_f32_16x16x32_bf16(         \
                    a[mt], b[nt], acc[mt][nt], 0, 0, 0);                       \
    }

    // ---- half 1: Agg x W_l ----
    STAGE_PANEL(Agg);
    __syncthreads();   // compiler drains vmcnt before barrier
    KHALF(0)

    // ---- half 2: Xb x W_r ----
    __syncthreads();   // all waves done reading half-1 panel
    STAGE_PANEL(Xb);
    __syncthreads();
    KHALF(256)
#undef KHALF
#undef STAGE_PANEL

    // ---- fused epilogue: bias + exact GELU + LayerNorm + residual(LDS) ----
    // C/D layout: col = lane&15, row = (lane>>4)*4 + reg
    float bl[4], ga[4], be[4];
#pragma unroll
    for (int nt = 0; nt < 4; nt++) {
        int c = wid * 64 + nt * 16 + lr;
        bl[nt] = b_l[c];
        ga[nt] = gamma[c];
        be[nt] = beta[c];
    }

#pragma unroll
    for (int mt = 0; mt < 4; mt++) {
#pragma unroll
        for (int r = 0; r < 4; r++) {
            float s = 0.f, q = 0.f;
#pragma unroll
            for (int nt = 0; nt < 4; nt++) {
                float u = acc[mt][nt][r] + bl[nt];
                float ge = 0.5f * u * (1.0f + erff(u * 0.70710678118654752f));
                acc[mt][nt][r] = ge;
                s += ge;
                q += ge * ge;
            }
#pragma unroll
            for (int off = 8; off >= 1; off >>= 1) {
                s += __shfl_xor(s, off, 64);
                q += __shfl_xor(q, off, 64);
            }
            if (lr == 0) {
                int rl = mt * 16 + lh * 4 + r;
                sm_s[wid][rl] = s;
                sm_q[wid][rl] = q;
            }
        }
    }
    __syncthreads();

#pragma unroll
    for (int mt = 0; mt < 4; mt++) {
#pragma unroll
        for (int r = 0; r < 4; r++) {
            int rl = mt * 16 + lh * 4 + r;
            int m = row0 + rl;
            float S = sm_s[0][rl] + sm_s[1][rl] + sm_s[2][rl] + sm_s[3][rl];
            float Q = sm_q[0][rl] + sm_q[1][rl] + sm_q[2][rl] + sm_q[3][rl];
            float mean = S * (1.0f / 256.0f);
            float var = Q * (1.0f / 256.0f) - mean * mean;
            float rstd = rsqrtf(var + 1e-5f);
            if (m < M) {
#pragma unroll
                for (int nt = 0; nt < 4; nt++) {
                    int c = wid * 64 + nt * 16 + lr;
                    int pb = (c >> 3) ^ ((rl & 7) << 2);  // Xb panel, swizzled
                    float res = (float)A_lds[rl * D + pb * 8 + (c & 7)];
                    out[(size_t)m * D + c] =
                        (acc[mt][nt][r] - mean) * rstd * ga[nt] + be[nt] + res;
                }
            }
        }
    }
}

// ---------------- launch ----------------

extern "C" void kernel_launch(void* const* d_in, const int* in_sizes, int n_in,
                              void* d_out, int out_size, void* d_ws, size_t ws_size,
                              hipStream_t stream) {
    const float* x = (const float*)d_in[0];
    const int* eidx = (const int*)d_in[1];
    const float* W_l = (const float*)d_in[2];
    const float* b_l = (const float*)d_in[3];
    const float* W_r = (const float*)d_in[4];
    const float* gamma = (const float*)d_in[5];
    const float* beta = (const float*)d_in[6];
    float* out = (float*)d_out;

    const int N = in_sizes[0] / D;
    const int E = in_sizes[1] / 2;
    const int B1 = (N + 255) >> 8;  // 256-node buckets

    char* basep = (char*)d_ws;
    size_t off = 0;
    auto take = [&](size_t bytes) -> void* {
        void* r = basep + off;
        off += (bytes + 255) & ~(size_t)255;
        return r;
    };
    bf16_t* Agg = (bf16_t*)take((size_t)N * D * sizeof(bf16_t));       // 51.2 MB
    bf16_t* Xb = (bf16_t*)take((size_t)N * D * sizeof(bf16_t));        // 51.2 MB
    unsigned int* Xq = (unsigned int*)take((size_t)N * (D / 4) * 4);   // 25.6 MB
    int* edge_src = (int*)take((size_t)E * sizeof(int));               // 12.8 MB
    bf16_t* Wcat = (bf16_t*)take((size_t)D * KDIM * sizeof(bf16_t));
    int* row_ptr = (int*)take((size_t)(N + 1) * sizeof(int));
    int* bcur = (int*)take((size_t)B1 * 16 * sizeof(int));
    int* bbase = (int*)take((size_t)B1 * sizeof(int));
    // staging (B1*BCAP ints = 25.6MB) aliases Agg (51.2MB): consumed by
    // k_bucket strictly BEFORE k_aggregate writes Agg.
    int* staging = (int*)Agg;

    hipMemsetAsync(bcur, 0, (size_t)B1 * 16 * sizeof(int), stream);

    k_scatter1<<<(E + EPB - 1) / EPB, 256, 0, stream>>>(eidx, bcur, staging, E);
    k_bbase<<<1, 512, 0, stream>>>(bcur, bbase, row_ptr, B1, N, E);
    k_bucket<<<B1, 256, 0, stream>>>(bcur, bbase, staging, edge_src, row_ptr, N);

    k_convx<<<(N * (D / 8) + 255) / 256, 256, 0, stream>>>(x, Xq, Xb, N * (D / 8));
    k_convw<<<(D * KDIM / 4 + 255) / 256, 256, 0, stream>>>(W_l, W_r, Wcat);

    k_aggregate<<<(N + 3) / 4, 256, 0, stream>>>(row_ptr, edge_src, Xq, Agg, N);

    k_gemm<<<(N + BM - 1) / BM, 256, 0, stream>>>(Agg, Xb, Wcat, b_l, gamma,
                                                  beta, out, N);
}

// Round 11
// 326.788 us; speedup vs baseline: 1.0872x; 1.0724x over previous
//
#include <hip/hip_runtime.h>

#define D 256
#define KDIM 512
#define BCAP 16384  // per-bucket staging capacity (avg fill 8192 for E=3.2M, B1=391)
#define EPB 8192    // edges per scatter block
#define BM 64       // rows per GEMM block

typedef __bf16 bf16_t;
typedef bf16_t bf16x8 __attribute__((ext_vector_type(8)));
typedef bf16_t bf16x4 __attribute__((ext_vector_type(4)));
typedef float f32x4_t __attribute__((ext_vector_type(4)));
typedef float f32x2_t __attribute__((ext_vector_type(2)));

// ---------------- CSR build (bucketed, block-aggregated scatter) -----------

__global__ __launch_bounds__(256) void k_scatter1(const int* __restrict__ eidx,
                                                  int* __restrict__ bcur,
                                                  int* __restrict__ staging, int E) {
    __shared__ int lhist[512];
    __shared__ int lcur[512];
    __shared__ int gbase[512];
    const int t = threadIdx.x;
    const int e0 = blockIdx.x * EPB;
    int e1 = e0 + EPB;
    if (e1 > E) e1 = E;

    lhist[t] = 0;
    lhist[t + 256] = 0;
    lcur[t] = 0;
    lcur[t + 256] = 0;
    __syncthreads();

    for (int e = e0 + t; e < e1; e += 256) {
        int d = eidx[E + e];
        atomicAdd(&lhist[d >> 8], 1);
    }
    __syncthreads();

#pragma unroll
    for (int b = t; b < 512; b += 256) {
        int c = lhist[b];
        gbase[b] = (c > 0) ? atomicAdd(&bcur[b * 16], c) : 0;
    }
    __syncthreads();

    for (int e = e0 + t; e < e1; e += 256) {
        int s = eidx[e];
        int d = eidx[E + e];
        int b = d >> 8;
        int pos = gbase[b] + atomicAdd(&lcur[b], 1);
        staging[(size_t)b * BCAP + pos] = ((d & 255) << 24) | s;  // s < 2^24
    }
}

__global__ __launch_bounds__(512) void k_bbase(const int* __restrict__ bcur,
                                               int* __restrict__ bbase,
                                               int* __restrict__ row_ptr,
                                               int B1, int N, int E) {
    __shared__ int sm[512];
    int t = threadIdx.x;
    int v = (t < B1) ? bcur[t * 16] : 0;
    sm[t] = v;
    __syncthreads();
    for (int off = 1; off < 512; off <<= 1) {
        int u = (t >= off) ? sm[t - off] : 0;
        __syncthreads();
        sm[t] += u;
        __syncthreads();
    }
    if (t < B1) bbase[t] = sm[t] - v;  // exclusive
    if (t == 0) row_ptr[N] = E;
}

__global__ __launch_bounds__(256) void k_bucket(const int* __restrict__ bcur,
                                                const int* __restrict__ bbase,
                                                const int* __restrict__ staging,
                                                int* __restrict__ edge_src,
                                                int* __restrict__ row_ptr, int N) {
    __shared__ int lhist[256];
    __shared__ int lscan[256];
    __shared__ int lcur[256];
    int b = blockIdx.x, t = threadIdx.x;
    int node_base = b << 8;
    int nn = N - node_base;
    if (nn > 256) nn = 256;
    int cnt = bcur[b * 16];
    int base = bbase[b];
    const int* stg = staging + (size_t)b * BCAP;

    lhist[t] = 0;
    __syncthreads();
    for (int i = t; i < cnt; i += 256)
        atomicAdd(&lhist[((unsigned)stg[i]) >> 24], 1);
    __syncthreads();
    int v = lhist[t];
    lscan[t] = v;
    __syncthreads();
    for (int off = 1; off < 256; off <<= 1) {
        int u = (t >= off) ? lscan[t - off] : 0;
        __syncthreads();
        lscan[t] += u;
        __syncthreads();
    }
    int excl = lscan[t] - v;
    if (t < nn) row_ptr[node_base + t] = base + excl;
    lscan[t] = excl;
    lcur[t] = 0;
    __syncthreads();
    for (int i = t; i < cnt; i += 256) {
        int w = stg[i];
        int ln = ((unsigned)w) >> 24;
        int src = w & 0xFFFFFF;
        int pos = base + lscan[ln] + atomicAdd(&lcur[ln], 1);
        edge_src[pos] = src;
    }
}

// ---------------- weights: Wcat2 [512][256] bf16 = [W_l ; W_r] rows --------

__global__ __launch_bounds__(256) void k_convw(const float* __restrict__ Wl,
                                               const float* __restrict__ Wr,
                                               bf16_t* __restrict__ Wcat2) {
    int i = blockIdx.x * 256 + threadIdx.x;
    if (i >= KDIM * D / 4) return;
    int o = i * 4;
    int j = o >> 8;   // output row 0..511
    int k = o & 255;  // k 0..255
    const float* src = (j < D) ? (Wl + (size_t)j * D + k)
                               : (Wr + (size_t)(j - D) * D + k);
    float4 v = *(const float4*)src;
    bf16x4 ov = {(bf16_t)v.x, (bf16_t)v.y, (bf16_t)v.z, (bf16_t)v.w};
    *(bf16x4*)(Wcat2 + o) = ov;
}

// ------- GEMM: H = x @ [W_l;W_r]^T.  Hl -> fp8 gather table, Hr+b_l -> bf16.
// 256 thr = 4 waves; block = 64 rows; A(x) staged ONCE into 32KB LDS
// (reg-staged f32->bf16, pre-swizzled blk^=(r&7)); two barrier-free k-loop
// passes (col halves); B = Wcat2 (256KB, L2-hot) direct-to-register. --------

__global__ __launch_bounds__(256) void k_gemm(
        const float* __restrict__ x, const bf16_t* __restrict__ Wcat2,
        const float* __restrict__ b_l, unsigned char* __restrict__ Hq,
        bf16_t* __restrict__ Hr, int M) {
    __shared__ __align__(16) bf16_t A_lds[BM * D];  // 32 KB

    const int tid = threadIdx.x;
    const int lane = tid & 63;
    const int wid = tid >> 6;   // wave -> 64-col strip (within each half)
    const int lr = lane & 15;
    const int lh = lane >> 4;
    const int row0 = blockIdx.x * BM;

    // ---- stage A panel once: 64 rows x 32 16B-blocks; slot j of row r holds
    // global block j^(r&7)  (linear LDS dest + inverse-swizzled source). ----
#pragma unroll
    for (int o = 0; o < 8; ++o) {
        int idx = o * 256 + tid;
        int r = idx >> 5;
        int j = idx & 31;
        int gr = row0 + r;
        if (gr > M - 1) gr = M - 1;
        int lb = j ^ (r & 7);
        float4 u0 = *(const float4*)(x + (size_t)gr * D + lb * 8);
        float4 u1 = *(const float4*)(x + (size_t)gr * D + lb * 8 + 4);
        bf16x8 v = {(bf16_t)u0.x, (bf16_t)u0.y, (bf16_t)u0.z, (bf16_t)u0.w,
                    (bf16_t)u1.x, (bf16_t)u1.y, (bf16_t)u1.z, (bf16_t)u1.w};
        *(bf16x8*)&A_lds[idx * 8] = v;
    }
    __syncthreads();

    f32x4_t acc[4][4];

#define KLOOP(COLOFF)                                                          \
    _Pragma("unroll") for (int k0 = 0; k0 < 256; k0 += 32) {                   \
        const int kb = (k0 >> 3) + lh;                                         \
        bf16x8 a[4], b[4];                                                     \
        _Pragma("unroll") for (int mt = 0; mt < 4; mt++) {                     \
            int ra = mt * 16 + lr;                                             \
            a[mt] = *(const bf16x8*)&A_lds[ra * D + ((kb ^ (ra & 7)) << 3)];   \
        }                                                                      \
        _Pragma("unroll") for (int nt = 0; nt < 4; nt++) {                     \
            int c = (COLOFF) + wid * 64 + nt * 16 + lr;                        \
            b[nt] = *(const bf16x8*)(Wcat2 + (size_t)c * D + k0 + lh * 8);     \
        }                                                                      \
        _Pragma("unroll") for (int mt = 0; mt < 4; mt++)                       \
            _Pragma("unroll") for (int nt = 0; nt < 4; nt++)                   \
                acc[mt][nt] = __builtin_amdgcn_mfma_f32_16x16x32_bf16(         \
                    a[mt], b[nt], acc[mt][nt], 0, 0, 0);                       \
    }

    // ---- pass 1: Hl = x @ W_l^T -> fp8 e4m3 bytes ----
#pragma unroll
    for (int i = 0; i < 4; i++)
#pragma unroll
        for (int j = 0; j < 4; j++) acc[i][j] = (f32x4_t){0.f, 0.f, 0.f, 0.f};
    KLOOP(0)
    // C/D layout: col = lane&15 (within 16-tile), row = (lane>>4)*4 + reg
#pragma unroll
    for (int mt = 0; mt < 4; mt++) {
#pragma unroll
        for (int r = 0; r < 4; r++) {
            int m = row0 + mt * 16 + lh * 4 + r;
            if (m < M) {
#pragma unroll
                for (int nt = 0; nt < 4; nt++) {
                    int c = wid * 64 + nt * 16 + lr;
                    float u = acc[mt][nt][r];
                    int w = __builtin_amdgcn_cvt_pk_fp8_f32(u, u, 0, false);
                    Hq[(size_t)m * D + c] = (unsigned char)(w & 0xff);
                }
            }
        }
    }

    // ---- pass 2: Hr = x @ W_r^T + b_l -> bf16 ----
    float bl[4];
#pragma unroll
    for (int nt = 0; nt < 4; nt++) bl[nt] = b_l[wid * 64 + nt * 16 + lr];
#pragma unroll
    for (int i = 0; i < 4; i++)
#pragma unroll
        for (int j = 0; j < 4; j++) acc[i][j] = (f32x4_t){0.f, 0.f, 0.f, 0.f};
    KLOOP(256)
#undef KLOOP
#pragma unroll
    for (int mt = 0; mt < 4; mt++) {
#pragma unroll
        for (int r = 0; r < 4; r++) {
            int m = row0 + mt * 16 + lh * 4 + r;
            if (m < M) {
#pragma unroll
                for (int nt = 0; nt < 4; nt++) {
                    int c = wid * 64 + nt * 16 + lr;
                    Hr[(size_t)m * D + c] = (bf16_t)(acc[mt][nt][r] + bl[nt]);
                }
            }
        }
    }
}

// ------- FINAL: wave-per-node gather-mean of Hq + Hr + GELU + LN + residual.
// After the g-group shfl combine, EVERY lane holds the full 16-elem chunk of
// column group c16 = lane&15; lane takes its 4 columns (compile-time selects)
// so the epilogue runs on all 64 lanes with zero LDS. ------------------------

__global__ __launch_bounds__(256) void k_final(
        const int* __restrict__ row_ptr, const int* __restrict__ edge_src,
        const unsigned char* __restrict__ Hq, const bf16_t* __restrict__ Hr,
        const float* __restrict__ x, const float* __restrict__ gamma,
        const float* __restrict__ beta, float* __restrict__ out, int N) {
    int wv = threadIdx.x >> 6;
    int lane = threadIdx.x & 63;
    int node = blockIdx.x * 4 + wv;
    if (node >= N) return;
    int g = lane >> 4;       // row subgroup in gather / column quad in epilogue
    int c16 = lane & 15;     // 16-fp8 column chunk
    int beg = row_ptr[node];
    int end = row_ptr[node + 1];
    const unsigned int* Hqw = (const unsigned int*)Hq;

    float acc[16];
#pragma unroll
    for (int k = 0; k < 16; k++) acc[k] = 0.f;

#define ACC4(w, bidx)                                            \
    {                                                            \
        f32x2_t lo = __builtin_amdgcn_cvt_pk_f32_fp8((w), false);\
        f32x2_t hi = __builtin_amdgcn_cvt_pk_f32_fp8((w), true); \
        acc[(bidx) + 0] += lo[0];                                \
        acc[(bidx) + 1] += lo[1];                                \
        acc[(bidx) + 2] += hi[0];                                \
        acc[(bidx) + 3] += hi[1];                                \
    }

    for (int j = beg; j < end; j += 8) {
        int j0 = j + g, j1 = j + 4 + g;
        bool ok0 = j0 < end, ok1 = j1 < end;
        int s0 = edge_src[ok0 ? j0 : beg];
        int s1 = edge_src[ok1 ? j1 : beg];
        uint4 v0 = *(const uint4*)(Hqw + (size_t)s0 * 64 + c16 * 4);
        uint4 v1 = *(const uint4*)(Hqw + (size_t)s1 * 64 + c16 * 4);
        if (!ok0) { v0.x = 0; v0.y = 0; v0.z = 0; v0.w = 0; }
        if (!ok1) { v1.x = 0; v1.y = 0; v1.z = 0; v1.w = 0; }
        ACC4(v0.x, 0) ACC4(v0.y, 4) ACC4(v0.z, 8) ACC4(v0.w, 12)
        ACC4(v1.x, 0) ACC4(v1.y, 4) ACC4(v1.z, 8) ACC4(v1.w, 12)
    }
#undef ACC4

    // combine the 4 row-subgroups -> all lanes hold the full chunk
#pragma unroll
    for (int k = 0; k < 16; k++) {
        acc[k] += __shfl_xor(acc[k], 16, 64);
        acc[k] += __shfl_xor(acc[k], 32, 64);
    }
    int dg = end - beg;
    float inv = 1.0f / (float)(dg > 0 ? dg : 1);

    // lane takes cols [col0, col0+4): agg-mean + Hr (bias folded) -> GELU
    int col0 = c16 * 16 + g * 4;
    bf16x4 hr = *(const bf16x4*)(Hr + (size_t)node * D + col0);
    float v[4];
    float s = 0.f, ss = 0.f;
#pragma unroll
    for (int j = 0; j < 4; j++) {
        float t = (g == 0) ? acc[j]
                : (g == 1) ? acc[4 + j]
                : (g == 2) ? acc[8 + j]
                           : acc[12 + j];
        float u = t * inv + (float)hr[j];
        float ge = 0.5f * u * (1.0f + erff(u * 0.70710678118654752f));
        v[j] = ge;
        s += ge;
        ss += ge * ge;
    }
    // full-wave LayerNorm reduction (all 64 lanes hold distinct columns)
#pragma unroll
    for (int off = 1; off <= 32; off <<= 1) {
        s += __shfl_xor(s, off, 64);
        ss += __shfl_xor(ss, off, 64);
    }
    float mean = s * (1.0f / 256.0f);
    float var = ss * (1.0f / 256.0f) - mean * mean;
    float rstd = rsqrtf(var + 1e-5f);

    float4 ga = *(const float4*)(gamma + col0);
    float4 be = *(const float4*)(beta + col0);
    float4 xr = *(const float4*)(x + (size_t)node * D + col0);
    float4 o;
#pragma unroll
    for (int j = 0; j < 4; j++)
        (&o.x)[j] = (v[j] - mean) * rstd * (&ga.x)[j] + (&be.x)[j] + (&xr.x)[j];
    *(float4*)(out + (size_t)node * D + col0) = o;
}

// ---------------- launch ----------------

extern "C" void kernel_launch(void* const* d_in, const int* in_sizes, int n_in,
                              void* d_out, int out_size, void* d_ws, size_t ws_size,
                              hipStream_t stream) {
    const float* x = (const float*)d_in[0];
    const int* eidx = (const int*)d_in[1];
    const float* W_l = (const float*)d_in[2];
    const float* b_l = (const float*)d_in[3];
    const float* W_r = (const float*)d_in[4];
    const float* gamma = (const float*)d_in[5];
    const float* beta = (const float*)d_in[6];
    float* out = (float*)d_out;

    const int N = in_sizes[0] / D;
    const int E = in_sizes[1] / 2;
    const int B1 = (N + 255) >> 8;  // 256-node buckets

    char* basep = (char*)d_ws;
    size_t off = 0;
    auto take = [&](size_t bytes) -> void* {
        void* r = basep + off;
        off += (bytes + 255) & ~(size_t)255;
        return r;
    };
    bf16_t* Hr = (bf16_t*)take((size_t)N * D * sizeof(bf16_t));        // 51.2 MB
    unsigned char* Hq = (unsigned char*)take((size_t)N * D);           // 25.6 MB
    int* edge_src = (int*)take((size_t)E * sizeof(int));               // 12.8 MB
    bf16_t* Wcat2 = (bf16_t*)take((size_t)KDIM * D * sizeof(bf16_t));  // 256 KB
    int* row_ptr = (int*)take((size_t)(N + 1) * sizeof(int));
    int* bcur = (int*)take((size_t)B1 * 16 * sizeof(int));
    int* bbase = (int*)take((size_t)B1 * sizeof(int));
    // staging (B1*BCAP ints = 25.6MB) aliases Hr (51.2MB): consumed by
    // k_bucket strictly BEFORE k_gemm writes Hr.
    int* staging = (int*)Hr;

    hipMemsetAsync(bcur, 0, (size_t)B1 * 16 * sizeof(int), stream);

    k_scatter1<<<(E + EPB - 1) / EPB, 256, 0, stream>>>(eidx, bcur, staging, E);
    k_bbase<<<1, 512, 0, stream>>>(bcur, bbase, row_ptr, B1, N, E);
    k_bucket<<<B1, 256, 0, stream>>>(bcur, bbase, staging, edge_src, row_ptr, N);

    k_convw<<<(KDIM * D / 4 + 255) / 256, 256, 0, stream>>>(W_l, W_r, Wcat2);

    k_gemm<<<(N + BM - 1) / BM, 256, 0, stream>>>(x, Wcat2, b_l, Hq, Hr, N);

    k_final<<<(N + 3) / 4, 256, 0, stream>>>(row_ptr, edge_src, Hq, Hr, x,
                                             gamma, beta, out, N);
}